// Round 14
// baseline (495.136 us; speedup 1.0000x reference)
//
#include <hip/hip_runtime.h>

#define B_TOT 65536
#define RS 44            // padded row stride (floats) for h / t rows
#define KDET 4

// per-wave LDS scratch ONLY (weights live in workspace/VMEM)
#define SC_STRIDE 1584   // t_s [0,1056) (h1 time-shares [128,896)) | hA [1056,1584)
#define LDS_FLOATS (4*SC_STRIDE)   // 6336 floats = 25344 B -> LDS allows 6 blocks/CU

// workspace layout (float4 units)
#define WS_F   0         // 12*11*64 = 8448 float4
#define WS_W2  8448      // 16*64    = 1024 float4
#define WS_W3  9472      // 16*32    =  512 float4
#define WS_TOT 9984

// pair enumeration p=0..14 : (n,m) lexicographic n<m
__device__ const int PN_TAB[15] = {0,0,0,0,0,1,1,1,1,2,2,2,3,3,4};
__device__ const int PM_TAB[15] = {1,2,3,4,5,2,3,4,5,3,4,5,4,5,5};
// matchings -> 3 pair indices; sign alternates +,-,+,...
__device__ const int M1_TAB[15] = {0,0,0,1,1,1,2,2,2,3,3,3,4,4,4};
__device__ const int M2_TAB[15] = {9,10,11,6,7,8,5,7,8,5,6,8,5,6,7};
__device__ const int M3_TAB[15] = {14,13,12,14,13,12,14,11,10,13,11,9,12,10,9};

__device__ __forceinline__ float bcastf(float v, int l) {
    return __int_as_float(__builtin_amdgcn_readlane(__float_as_int(v), l));
}
// wave-local LDS ordering only; vmcnt NOT drained
#define WFENCE() asm volatile("s_waitcnt lgkmcnt(0)" ::: "memory")

// prep: F~ swizzled [sk][c][d] float4; W2 packed [i4][lane]; W3 packed [i4][j2]
__global__ void prep_all(const float* __restrict__ dFud, const float* __restrict__ dFuu,
                         const float* __restrict__ dFdd, const float* __restrict__ Phf,
                         const float* __restrict__ W2, const float* __restrict__ W3,
                         float4* __restrict__ ws)
{
    int t = blockIdx.x * 256 + threadIdx.x;
    if (t < 12*11*64) {
        int d  = t & 63;
        int c  = (t >> 6) % 11;
        int sk = t / (11*64);
        int s = sk >> 2, k = sk & 3;
        const float* src = (s==0) ? dFuu : (s==1) ? dFdd : dFud;
        float v[4];
        #pragma unroll
        for (int j=0;j<4;j++){
            int e = 4*c + j;
            float r = 0.f;
            if (d < 41 && e < 41) {
                if (s < 2) r = 0.01f * (src[(k*41+d)*41+e] - src[(k*41+e)*41+d]);
                else     { r = 0.01f *  src[(k*41+d)*41+e]; if (k==0) r += Phf[d*41+e]; }
            }
            v[j] = r;
        }
        ws[WS_F + t] = make_float4(v[0],v[1],v[2],v[3]);
    } else if (t < 12*11*64 + 1024) {
        int u = t - 12*11*64;
        int i4 = u >> 6, j = u & 63;
        ws[WS_W2 + u] = make_float4(W2[(4*i4+0)*64 + j], W2[(4*i4+1)*64 + j],
                                    W2[(4*i4+2)*64 + j], W2[(4*i4+3)*64 + j]);
    } else if (t < WS_TOT) {
        int u = t - (12*11*64 + 1024);
        int i4 = u >> 5, j2 = u & 31;
        ws[WS_W3 + u] = make_float4(W3[(4*i4+0)*32 + j2], W3[(4*i4+1)*32 + j2],
                                    W3[(4*i4+2)*32 + j2], W3[(4*i4+3)*32 + j2]);
    }
}

// (256,4): VGPR cap 64, residency 4 waves/SIMD -> 16 waves/CU (LDS allows it).
// Body engineered to ~64 live VGPRs: F row = 41 regs, packed tabs, 6 persistents.
__global__ __launch_bounds__(256, 4)
void pfaff_main(const float* __restrict__ x, const int* __restrict__ spin,
                const float* __restrict__ se, const float* __restrict__ W1,
                const float* __restrict__ b1, const float* __restrict__ b2,
                const float* __restrict__ b3, const float* __restrict__ wdet,
                const float4* __restrict__ ws, float* __restrict__ out)
{
    __shared__ __align__(16) float lds[LDS_FLOATS];
    const int tid  = threadIdx.x;
    const int wave = tid >> 6, lane = tid & 63;
    float* sc  = lds + wave*SC_STRIDE;
    float* t_s = sc;            // [0,1056)
    float* h1  = sc + 128;      // [128,896) (time-shared with t_s)
    float* hA  = sc + 1056;     // [1056,1584)

    for (int i = lane; i < SC_STRIDE; i += 64) sc[i] = 0.f;
    WFENCE();

    const float4* wsF  = ws + WS_F;
    const float4* wsW2 = ws + WS_W2;
    const float4* wsW3 = ws + WS_W3;

    // ---- persistents (6 VGPR): W1 x/y columns + emb(+b1) per spin ----
    const float w1c0 = W1[lane], w1c1 = W1[64 + lane];
    float emb0 = b1[lane], emb1 = emb0;
    #pragma unroll
    for (int j=0;j<8;j++){
        float wv = W1[(2+j)*64 + lane];
        emb0 = fmaf(wv, se[j],   emb0);
        emb1 = fmaf(wv, se[8+j], emb1);
    }
    const float b2r = b2[lane];
    const float b3r = b3[lane & 31];
    // packed pair/matching tables: 5 x 5-bit fields in one VGPR
    int pk = 0;
    {
        const int p_ = lane & 31;
        if (p_ < 15) pk = PN_TAB[p_] | (PM_TAB[p_]<<5) | (M1_TAB[p_]<<10)
                        | (M2_TAB[p_]<<15) | (M3_TAB[p_]<<20);
    }

    const int ebase = ((int)blockIdx.x * 4 + wave) * 4;
    #pragma unroll 1
    for (int pi = 0; pi < 2; ++pi) {
        const int e0 = ebase + pi*2;

        // ---- P0: particle data for 2 elements; Phi -> hA rows ----
        int s_n = 0; float xx = 0.f, xy = 0.f;
        if (lane < 12) {
            int gg = lane >= 6;
            int eg = e0 + gg;
            int n  = lane - gg*6;
            float2 xv = *(const float2*)(x + (size_t)(eg*6 + n)*2);
            xx = xv.x; xy = xv.y;
            s_n = spin[eg*6 + n];
        }
        unsigned long long bal = __ballot(lane < 12 && s_n == 1);
        const unsigned dn0 = (unsigned)__builtin_amdgcn_readfirstlane((int)((unsigned)bal & 63u));
        const unsigned dn1 = (unsigned)__builtin_amdgcn_readfirstlane((int)((unsigned)(bal >> 6) & 63u));

        if (lane < 12) {
            float ex = __expf(-0.5f*(xx*xx));
            float px0 = 0.7511255444649425f * ex;
            float px1 = 1.4142135623730951f * xx * px0;
            float px2 = fmaf(xx, px1, -0.7071067811865476f * px0);
            float ey = __expf(-0.5f*(xy*xy));
            float py0 = 0.7511255444649425f * ey;
            float py1 = 1.4142135623730951f * xy * py0;
            float py2 = fmaf(xy, py1, -0.7071067811865476f * py0);
            float* hr = hA + lane*RS;
            hr[0]=px0*py0; hr[1]=px0*py1; hr[2]=px0*py2;
            hr[3]=px1*py0; hr[4]=px1*py1; hr[5]=px1*py2;
            hr[6]=px2*py0; hr[7]=px2*py1; hr[8]=px2*py2;
            hr[41]=0.f; hr[42]=0.f; hr[43]=0.f;
        }

        // ---- L1 (10->64): registers via readlane; write h1 to LDS ----
        #pragma unroll
        for (int r=0;r<12;r++){
            float xr = bcastf(xx, r);
            float yr = bcastf(xy, r);
            int   sr = __builtin_amdgcn_readlane(s_n, r);
            float a  = fmaf(xr, w1c0, (sr ? emb1 : emb0));
            a = fmaf(yr, w1c1, a);
            h1[r*64 + lane] = __fdividef(a, 1.f + __expf(-a));
        }
        WFENCE();

        // ---- L2 (64->64): W2 via VMEM packed, h via uniform LDS b128 ----
        float acc[12];
        #pragma unroll
        for (int r=0;r<12;r++) acc[r] = b2r;
        #pragma unroll 1
        for (int i4=0;i4<16;i4++){
            float4 w4 = wsW2[i4*64 + lane];
            #pragma unroll
            for (int r=0;r<12;r++){
                float4 h4 = *(const float4*)(h1 + r*64 + i4*4);
                acc[r]=fmaf(w4.x,h4.x,acc[r]); acc[r]=fmaf(w4.y,h4.y,acc[r]);
                acc[r]=fmaf(w4.z,h4.z,acc[r]); acc[r]=fmaf(w4.w,h4.w,acc[r]);
            }
        }
        WFENCE();
        #pragma unroll
        for (int r=0;r<12;r++){
            float v = acc[r];
            h1[r*64 + lane] = __fdividef(v, 1.f + __expf(-v));
        }
        WFENCE();

        // ---- L3 (64->32): half-wave per element; W3 via VMEM packed ----
        {
            int j2 = lane & 31, hf = lane >> 5;
            float a3[6];
            #pragma unroll
            for (int rr=0;rr<6;rr++) a3[rr] = b3r;
            #pragma unroll 1
            for (int i4=0;i4<16;i4++){
                float4 w4 = wsW3[i4*32 + j2];
                #pragma unroll
                for (int rr=0;rr<6;rr++){
                    float4 h4 = *(const float4*)(h1 + (hf*6+rr)*64 + i4*4);
                    a3[rr]=fmaf(w4.x,h4.x,a3[rr]); a3[rr]=fmaf(w4.y,h4.y,a3[rr]);
                    a3[rr]=fmaf(w4.z,h4.z,a3[rr]); a3[rr]=fmaf(w4.w,h4.w,a3[rr]);
                }
            }
            #pragma unroll
            for (int rr=0;rr<6;rr++) hA[(hf*6+rr)*RS + 9 + j2] = a3[rr];
        }
        WFENCE();

        // ---- bilinear + pfaffian: h via uniform ds_read broadcasts ----
        float total = 0.f;
        #pragma unroll 1
        for (int k = 0; k < KDET; ++k) {
            #pragma unroll 1
            for (int pass=0; pass<3; ++pass) {
                const float4* Fp = wsF + (size_t)(pass*4 + k)*(11*64) + lane;
                float4 fA=Fp[0],    fB=Fp[64],   fC=Fp[2*64], fD=Fp[3*64];
                float4 fE=Fp[4*64], fF=Fp[5*64], fG=Fp[6*64], fH=Fp[7*64];
                float4 fI=Fp[8*64], fJ=Fp[9*64];
                const float fK0 = *((const float*)(Fp + 10*64));   // col 40 (41..43 zero)
                const int dstb = (pass==2) ? 6 : 0;
                #pragma unroll
                for (int gg=0; gg<2; ++gg){
                    const unsigned dng = gg ? dn1 : dn0;
                    const unsigned mk  = pass ? dng : ((~dng) & 63u);
                    #pragma unroll
                    for (int m=0;m<6;m++){
                        if ((mk>>m)&1) {
                            const float* hm = hA + (gg*6+m)*RS;
                            float4 q;
                            float a0, a1, a2, a3v;
                            q = *(const float4*)(hm);
                            a0  = fA.x*q.x; a1 = fA.y*q.y;
                            a2  = fA.z*q.z; a3v= fA.w*q.w;
                            q = *(const float4*)(hm+4);
                            a0=fmaf(fB.x,q.x,a0); a1=fmaf(fB.y,q.y,a1);
                            a2=fmaf(fB.z,q.z,a2); a3v=fmaf(fB.w,q.w,a3v);
                            q = *(const float4*)(hm+8);
                            a0=fmaf(fC.x,q.x,a0); a1=fmaf(fC.y,q.y,a1);
                            a2=fmaf(fC.z,q.z,a2); a3v=fmaf(fC.w,q.w,a3v);
                            q = *(const float4*)(hm+12);
                            a0=fmaf(fD.x,q.x,a0); a1=fmaf(fD.y,q.y,a1);
                            a2=fmaf(fD.z,q.z,a2); a3v=fmaf(fD.w,q.w,a3v);
                            q = *(const float4*)(hm+16);
                            a0=fmaf(fE.x,q.x,a0); a1=fmaf(fE.y,q.y,a1);
                            a2=fmaf(fE.z,q.z,a2); a3v=fmaf(fE.w,q.w,a3v);
                            q = *(const float4*)(hm+20);
                            a0=fmaf(fF.x,q.x,a0); a1=fmaf(fF.y,q.y,a1);
                            a2=fmaf(fF.z,q.z,a2); a3v=fmaf(fF.w,q.w,a3v);
                            q = *(const float4*)(hm+24);
                            a0=fmaf(fG.x,q.x,a0); a1=fmaf(fG.y,q.y,a1);
                            a2=fmaf(fG.z,q.z,a2); a3v=fmaf(fG.w,q.w,a3v);
                            q = *(const float4*)(hm+28);
                            a0=fmaf(fH.x,q.x,a0); a1=fmaf(fH.y,q.y,a1);
                            a2=fmaf(fH.z,q.z,a2); a3v=fmaf(fH.w,q.w,a3v);
                            q = *(const float4*)(hm+32);
                            a0=fmaf(fI.x,q.x,a0); a1=fmaf(fI.y,q.y,a1);
                            a2=fmaf(fI.z,q.z,a2); a3v=fmaf(fI.w,q.w,a3v);
                            q = *(const float4*)(hm+36);
                            a0=fmaf(fJ.x,q.x,a0); a1=fmaf(fJ.y,q.y,a1);
                            a2=fmaf(fJ.z,q.z,a2); a3v=fmaf(fJ.w,q.w,a3v);
                            a0 = fmaf(fK0, hm[40], a0);
                            float t = (a0+a1)+(a2+a3v);
                            if (lane < RS)
                                t_s[(gg*12 + dstb + m)*RS + lane] = (lane < 41) ? t : 0.f;
                        }
                    }
                }
            }
            WFENCE();

            // ---- A[pair] both elements: lanes (g*32+p), p<15 ----
            const int p = lane & 31, g = lane >> 5;
            const int pn  =  pk        & 31;
            const int pm  = (pk >> 5)  & 31;
            float av = 0.f;
            if (p < 15) {
                unsigned dng = g ? dn1 : dn0;
                int sn = (int)((dng>>pn)&1), sm = (int)((dng>>pm)&1);
                int hrow, trow; float sg;
                if (sn == sm)      { hrow = pn; trow = pm;     sg =  1.f; }
                else if (sn == 0)  { hrow = pn; trow = 6 + pm; sg =  1.f; }
                else               { hrow = pm; trow = 6 + pn; sg = -1.f; }
                const float4* hp = (const float4*)(hA  + (g*6  + hrow)*RS);
                const float4* tp = (const float4*)(t_s + (g*12 + trow)*RS);
                float a0=0.f,a1=0.f,a2=0.f,a3v=0.f;
                #pragma unroll
                for (int q=0;q<11;q++){
                    float4 hv = hp[q]; float4 tv = tp[q];
                    a0=fmaf(hv.x,tv.x,a0); a1=fmaf(hv.y,tv.y,a1);
                    a2=fmaf(hv.z,tv.z,a2); a3v=fmaf(hv.w,tv.w,a3v);
                }
                av = sg * ((a0+a1)+(a2+a3v));
            }
            int g32 = lane & 32;
            float q1 = __shfl(av, g32 + ((pk >> 10) & 31));
            float q2 = __shfl(av, g32 + ((pk >> 15) & 31));
            float q3 = __shfl(av, g32 + ((pk >> 20) & 31));
            float term = 0.f;
            if (p < 15) { float pr = q1*q2*q3; term = (p & 1) ? -pr : pr; }
            term += __shfl_xor(term, 1);
            term += __shfl_xor(term, 2);
            term += __shfl_xor(term, 4);
            term += __shfl_xor(term, 8);
            total = fmaf(wdet[k], term, total);
            WFENCE();
        }

        if ((lane & 31) == 0) {
            int e = e0 + (lane >> 5);
            float sgn = (total > 0.f) ? 1.f : ((total < 0.f) ? -1.f : 1.f);
            out[e]         = sgn;
            out[B_TOT + e] = 0.5f * logf(fmaf(total, total, 1e-60f));
        }
        WFENCE();
    }
}

extern "C" void kernel_launch(void* const* d_in, const int* in_sizes, int n_in,
                              void* d_out, int out_size, void* d_ws, size_t ws_size,
                              hipStream_t stream)
{
    const float* x    = (const float*)d_in[0];
    const int*   spin = (const int*)  d_in[1];
    const float* se   = (const float*)d_in[2];
    const float* W1   = (const float*)d_in[3];
    const float* b1   = (const float*)d_in[4];
    const float* W2   = (const float*)d_in[5];
    const float* b2   = (const float*)d_in[6];
    const float* W3   = (const float*)d_in[7];
    const float* b3   = (const float*)d_in[8];
    const float* Phf  = (const float*)d_in[9];
    const float* dFud = (const float*)d_in[10];
    const float* dFuu = (const float*)d_in[11];
    const float* dFdd = (const float*)d_in[12];
    const float* w    = (const float*)d_in[13];
    float* out = (float*)d_out;
    float4* ws = (float4*)d_ws;

    hipLaunchKernelGGL(prep_all, dim3(39), dim3(256), 0, stream,
                       dFud, dFuu, dFdd, Phf, W2, W3, ws);
    hipLaunchKernelGGL(pfaff_main, dim3(4096), dim3(256), 0, stream,
                       x, spin, se, W1, b1, b2, b3, w, ws, out);
}